// Round 1
// baseline (71.245 us; speedup 1.0000x reference)
//
#include <hip/hip_runtime.h>

// Problem constants (from reference)
#define NXD 2048
#define NYD 2048
#define DIMD 28
// Tile: 32 i-rows x 128 j-cols per 256-thread block
#define TI 32
#define TJ 128

// class nibble table: v -> class, classes = [1,1,1,0,0,0,0,2] packed low->high
#define CLS_TABLE 0x20000111u

__global__ __launch_bounds__(256) void setdist_kernel(
    const int* __restrict__ set_r,
    const int* __restrict__ set_t,
    const float* __restrict__ sigma_p,
    float* __restrict__ out)
{
    // AoS packs: [row][0..3]=one-hot(8b/pos) eq-mask, [row][4..5]=one-hot(4b/pos) class-mask
    __shared__ unsigned long long r_pk[TI][6];
    __shared__ unsigned long long t_pk[TJ][6];

    const int tid = threadIdx.x;
    const int i0 = blockIdx.y * TI;
    const int j0 = blockIdx.x * TJ;

    // ---- pack phase: threads 0..TI-1 pack r-rows, TI..TI+TJ-1 pack t-rows ----
    if (tid < TI + TJ) {
        const bool isR = (tid < TI);
        const int row = isR ? (i0 + tid) : (j0 + (tid - TI));
        const int* src = (isR ? set_r : set_t) + row * DIMD;

        // 28 ints = 7 x int4, row start is 112-byte offset -> 16B aligned
        int vals[DIMD];
        const int4* s4 = (const int4*)src;
        #pragma unroll
        for (int q = 0; q < 7; ++q) {
            int4 w = s4[q];
            vals[4*q + 0] = w.x; vals[4*q + 1] = w.y;
            vals[4*q + 2] = w.z; vals[4*q + 3] = w.w;
        }

        unsigned long long eq0 = 0, eq1 = 0, eq2 = 0, eq3 = 0;
        unsigned long long cl0 = 0, cl1 = 0;
        #pragma unroll
        for (int d = 0; d < DIMD; ++d) {
            const int v = vals[d];
            const int b = d * 8 + v;           // 0..223
            const unsigned long long bit = 1ull << (b & 63);
            switch (b >> 6) {
                case 0: eq0 |= bit; break;
                case 1: eq1 |= bit; break;
                case 2: eq2 |= bit; break;
                default: eq3 |= bit; break;
            }
            const int c = (CLS_TABLE >> (4 * v)) & 0xF;  // 0..2
            const int bc = d * 4 + c;          // 0..111
            if (bc < 64) cl0 |= 1ull << bc;
            else         cl1 |= 1ull << (bc - 64);
        }
        unsigned long long* dst = isR ? r_pk[tid] : t_pk[tid - TI];
        dst[0] = eq0; dst[1] = eq1; dst[2] = eq2; dst[3] = eq3;
        dst[4] = cl0; dst[5] = cl1;
    }

    const float sg = sigma_p[0];
    // out = exp(-((56-s)/28)^2 / (2*sigma^2)) = exp(-(56-s)^2 * k)
    const float k = 1.0f / (2.0f * sg * sg * 28.0f * 28.0f);

    __syncthreads();

    // ---- compute phase: thread -> (jj, 16 consecutive i-rows) ----
    const int jj = tid & (TJ - 1);
    const int iBase = (tid >> 7) * 16;   // 0 or 16

    const unsigned long long te0 = t_pk[jj][0];
    const unsigned long long te1 = t_pk[jj][1];
    const unsigned long long te2 = t_pk[jj][2];
    const unsigned long long te3 = t_pk[jj][3];
    const unsigned long long tc0 = t_pk[jj][4];
    const unsigned long long tc1 = t_pk[jj][5];

    float* orow = out + (size_t)(i0 + iBase) * NYD + (j0 + jj);

    #pragma unroll
    for (int u = 0; u < 16; ++u) {
        const int il = iBase + u;   // wave-uniform -> LDS broadcast, conflict-free
        const int s =
            __popcll(r_pk[il][0] & te0) + __popcll(r_pk[il][1] & te1) +
            __popcll(r_pk[il][2] & te2) + __popcll(r_pk[il][3] & te3) +
            __popcll(r_pk[il][4] & tc0) + __popcll(r_pk[il][5] & tc1);
        const float c = (float)(56 - s);
        orow[(size_t)u * NYD] = __expf(-c * c * k);
    }
}

extern "C" void kernel_launch(void* const* d_in, const int* in_sizes, int n_in,
                              void* d_out, int out_size, void* d_ws, size_t ws_size,
                              hipStream_t stream) {
    const int*   set_r = (const int*)d_in[0];
    const int*   set_t = (const int*)d_in[1];
    const float* sigma = (const float*)d_in[2];
    float*       out   = (float*)d_out;

    dim3 grid(NYD / TJ, NXD / TI);   // (16, 64) = 1024 blocks
    dim3 block(256);
    setdist_kernel<<<grid, block, 0, stream>>>(set_r, set_t, sigma, out);
}